// Round 10
// baseline (214.647 us; speedup 1.0000x reference)
//
#include <hip/hip_runtime.h>
#include <cstdint>
#include <cstddef>
#include <math.h>

typedef __attribute__((ext_vector_type(8))) __bf16 bf16x8;
typedef __attribute__((ext_vector_type(4))) __bf16 bf16x4;
typedef __attribute__((ext_vector_type(4))) float f32x4;
typedef __attribute__((ext_vector_type(4))) unsigned int u32x4;

#define AS1 __attribute__((address_space(1)))
#define AS3 __attribute__((address_space(3)))

#define LOG2E 1.4426950408889634f

__device__ __forceinline__ void gld16(void* lds_uniform, const void* gaddr) {
  __builtin_amdgcn_global_load_lds((const AS1 unsigned int*)gaddr,
                                   (AS3 unsigned int*)lds_uniform, 16, 0, 0);
}

// ---------------------------------------------------------------- prep: fp32->bf16 casts only
// (bias rearrange DELETED: attn reads the original f32 bias directly -> -96MB HBM traffic)
__global__ __launch_bounds__(256)
void prep_kernel(const float* __restrict__ x, const float* __restrict__ wqkv,
                 const float* __restrict__ wproj,
                 __bf16* __restrict__ xb, __bf16* __restrict__ wqkvb,
                 __bf16* __restrict__ wprojb) {
  const int b = blockIdx.x;
  const int tid = threadIdx.x;
  const float* src; __bf16* dst; int fb;
  if (b < 1024)      { src = x;     dst = xb;     fb = b; }
  else if (b < 1792) { src = wqkv;  dst = wqkvb;  fb = b - 1024; }
  else               { src = wproj; dst = wprojb; fb = b - 1792; }
#pragma unroll
  for (int q = 0; q < 4; ++q) {
    const size_t i = ((size_t)fb * 1024 + q * 256 + tid) * 4;
    const float4 v = *(const float4*)(src + i);
    bf16x4 o;
    o[0] = (__bf16)v.x; o[1] = (__bf16)v.y; o[2] = (__bf16)v.z; o[3] = (__bf16)v.w;
    *(bf16x4*)(dst + i) = o;
  }
}

// ---------------------------------------------------------------- QKV GEMM v5 (verified): 4-wave, 64x64/wave,
// BK=64, grid 768, bijective XCD swizzle, launch_bounds(256,3) -> 3 blocks/CU, V epilogue
// staged through wave-private LDS for coalesced bf16x8 stores.
__global__ __launch_bounds__(256, 3)
void gemm_qkv_kernel(const __bf16* __restrict__ A, const __bf16* __restrict__ B,
                     const float* __restrict__ q_bias, const float* __restrict__ v_bias,
                     const float* __restrict__ scale_mul,
                     __bf16* __restrict__ qb, __bf16* __restrict__ ktp, __bf16* __restrict__ vtp) {
  __shared__ __attribute__((aligned(16))) __bf16 As[2][128 * 32];
  __shared__ __attribute__((aligned(16))) __bf16 Bs[2][128 * 32];
  const int tid = threadIdx.x;
  const int w = tid >> 6, lane = tid & 63;
  const int bid = blockIdx.x;
  const int swz = (bid & 7) * 96 + (bid >> 3);    // 768 % 8 == 0 -> bijective
  const int m0 = (swz / 24) * 128, n0 = (swz % 24) * 128;
  const int wm = (w >> 1) * 64, wn = (w & 1) * 64;
  const int c = lane & 15, g = lane >> 4;
  f32x4 acc[4][4];  // [ni][mi]
#pragma unroll
  for (int i = 0; i < 4; ++i)
#pragma unroll
    for (int j = 0; j < 4; ++j) acc[i][j] = (f32x4)(0.0f);

  const int r_row = lane >> 2;
  const int r_col = (lane & 3) * 16;
  const char* Abase = (const char*)A + (size_t)m0 * 2048;
  const char* Bbase = (const char*)B + (size_t)n0 * 2048;

  for (int kt = 0; kt < 1024; kt += 64) {
#pragma unroll
    for (int ks = 0; ks < 2; ++ks)
#pragma unroll
      for (int s = 0; s < 2; ++s) {
        const int R = w * 2 + s;
        const int row = R * 16 + r_row;
        gld16((char*)&As[ks][0] + R * 1024, Abase + (size_t)row * 2048 + kt * 2 + ks * 64 + r_col);
        gld16((char*)&Bs[ks][0] + R * 1024, Bbase + (size_t)row * 2048 + kt * 2 + ks * 64 + r_col);
      }
    __syncthreads();
#pragma unroll
    for (int ks = 0; ks < 2; ++ks) {
      bf16x8 af[4], bfr[4];
#pragma unroll
      for (int i = 0; i < 4; ++i) {
        af[i]  = *(const bf16x8*)((const char*)&As[ks][0] + (wm + i * 16 + c) * 64 + g * 16);
        bfr[i] = *(const bf16x8*)((const char*)&Bs[ks][0] + (wn + i * 16 + c) * 64 + g * 16);
      }
#pragma unroll
      for (int ni = 0; ni < 4; ++ni)
#pragma unroll
        for (int mi = 0; mi < 4; ++mi)
          acc[ni][mi] = __builtin_amdgcn_mfma_f32_16x16x32_bf16(bfr[ni], af[mi], acc[ni][mi], 0, 0, 0);
    }
    __syncthreads();
  }

  const int nbase = n0 + wn;
  const int which = nbase >> 10;
  const int h = (nbase >> 6) & 15;
  float smh = 1.0f;
  if (which == 0) smh = __expf(fminf(scale_mul[h], 4.605170185988091f)) * LOG2E;
  float4 cb[4];
#pragma unroll
  for (int ni = 0; ni < 4; ++ni) {
    if (which == 0)      cb[ni] = *(const float4*)(q_bias + nbase + ni * 16 + 4 * g);
    else if (which == 2) cb[ni] = *(const float4*)(v_bias + nbase - 2048 + ni * 16 + 4 * g);
    else                 cb[ni] = make_float4(0.f, 0.f, 0.f, 0.f);
  }
  const int mrow0 = m0 + wm;
  const int b2 = mrow0 >> 11;
  const int lpos0 = mrow0 & 2047;
  __bf16* kt_tile = ktp + (size_t)(b2 * 16 + h) * 131072 + (size_t)(lpos0 >> 6) * 4096;
  __bf16* dst_q = qb + ((size_t)((b2 * 16 + h) * 2048 + lpos0)) * 64;
  __bf16* vtile = vtp + ((size_t)((b2 * 16 + h) * 32) + (lpos0 >> 6)) * 4096;
  __bf16* Ls = (__bf16*)((char*)&As[0][0] + w * 8192);  // wave-private, dead after K-loop

#pragma unroll
  for (int mi = 0; mi < 4; ++mi) {
    float v[4][4];
#pragma unroll
    for (int ni = 0; ni < 4; ++ni) {
      v[ni][0] = acc[ni][mi][0] + cb[ni].x;
      v[ni][1] = acc[ni][mi][1] + cb[ni].y;
      v[ni][2] = acc[ni][mi][2] + cb[ni].z;
      v[ni][3] = acc[ni][mi][3] + cb[ni].w;
    }
    const int key = mi * 16 + c;
    if (which == 2) {
      // V: stage to wave-private LDS in slot order (sc == 1, no normalize)
      const int ks2 = mi >> 1;
      const int gg  = ((mi & 1) << 1) | (c >> 3);
      const int e   = c & 7;
      __bf16* basep = Ls + ks2 * 2048 + gg * 8 + e;
#pragma unroll
      for (int ni = 0; ni < 4; ++ni)
#pragma unroll
        for (int j = 0; j < 4; ++j)
          basep[ni * 512 + (4 * g + j) * 32] = (__bf16)v[ni][j];
    } else {
      float ss = 0.0f;
#pragma unroll
      for (int ni = 0; ni < 4; ++ni)
#pragma unroll
        for (int j = 0; j < 4; ++j) ss += v[ni][j] * v[ni][j];
      ss += __shfl_xor(ss, 16, 64);
      ss += __shfl_xor(ss, 32, 64);
      const float sc = rsqrtf(ss) * smh;
      if (which == 1) {
#pragma unroll
        for (int ni = 0; ni < 4; ++ni) {
          bf16x4 pk;
          pk[0] = (__bf16)(v[ni][0] * sc); pk[1] = (__bf16)(v[ni][1] * sc);
          pk[2] = (__bf16)(v[ni][2] * sc); pk[3] = (__bf16)(v[ni][3] * sc);
          *(bf16x4*)(kt_tile + (ni >> 1) * 2048 + key * 32 + (ni & 1) * 16 + 4 * g) = pk;
        }
      } else {
        __bf16* drow = dst_q + (size_t)key * 64;
#pragma unroll
        for (int ni = 0; ni < 4; ++ni) {
          bf16x4 pk;
          pk[0] = (__bf16)(v[ni][0] * sc); pk[1] = (__bf16)(v[ni][1] * sc);
          pk[2] = (__bf16)(v[ni][2] * sc); pk[3] = (__bf16)(v[ni][3] * sc);
          *(bf16x4*)(drow + ni * 16 + 4 * g) = pk;
        }
      }
    }
  }
  if (which == 2) {
    // coalesced readback + store: 8 x 1KB bf16x8 per wave
#pragma unroll
    for (int r = 0; r < 8; ++r) {
      const int o = r * 512 + lane * 8;
      *(bf16x8*)(vtile + o) = *(const bf16x8*)(Ls + o);
    }
  }
}

// ---------------------------------------------------------------- flash attention v16
// = v13 (verified best) with bias read DIRECTLY from the original f32 tensor:
// lane (c,g) needs row q0+c (fixed), cols t*64 + ni*16 + g*4 + {0..3} -> one float4/ni.
// *LOG2E folds into fmaf before exp2. btr buffer + prep bias pass deleted.
#define STAGE(t, b) {                                                          \
  const char* _ks = kp + (size_t)(t) * 8192 + w * 1024 + sl16;                 \
  const char* _vs = vp + (size_t)(t) * 8192 + w * 1024 + sl16;                 \
  gld16(&Kb[b][w * 1024], _ks);                                                \
  gld16(&Vb[b][w * 1024], _vs);                                                \
}

#define COMPUTE(t, b) {                                                        \
  const float* _bb = bprow + (t) * 64 + g * 4;                                 \
  f32x4 bF[4];                                                                 \
  _Pragma("unroll")                                                            \
  for (int ni = 0; ni < 4; ++ni) bF[ni] = *(const f32x4*)(_bb + ni * 16);      \
  bf16x8 kf[4][2];                                                             \
  _Pragma("unroll")                                                            \
  for (int ni = 0; ni < 4; ++ni)                                               \
    _Pragma("unroll")                                                          \
    for (int ks = 0; ks < 2; ++ks)                                             \
      kf[ni][ks] = *(const bf16x8*)(&Kb[b][0] + ks * 4096 + (ni * 16 + c) * 64 + gsw16); \
  f32x4 sacc[4];                                                               \
  __builtin_amdgcn_s_setprio(1);                                               \
  _Pragma("unroll")                                                            \
  for (int ni = 0; ni < 4; ++ni) {                                             \
    f32x4 s_ = __builtin_amdgcn_mfma_f32_16x16x32_bf16(kf[ni][0], qf[0], (f32x4)(0.0f), 0, 0, 0); \
    sacc[ni] = __builtin_amdgcn_mfma_f32_16x16x32_bf16(kf[ni][1], qf[1], s_, 0, 0, 0); \
  }                                                                            \
  __builtin_amdgcn_s_setprio(0);                                               \
  unsigned qp[4][2];                                                           \
  _Pragma("unroll")                                                            \
  for (int ni = 0; ni < 4; ++ni) {                                             \
    const float p0 = __builtin_amdgcn_exp2f(fmaf(bF[ni][0], LOG2E, sacc[ni][0])); \
    const float p1 = __builtin_amdgcn_exp2f(fmaf(bF[ni][1], LOG2E, sacc[ni][1])); \
    const float p2 = __builtin_amdgcn_exp2f(fmaf(bF[ni][2], LOG2E, sacc[ni][2])); \
    const float p3 = __builtin_amdgcn_exp2f(fmaf(bF[ni][3], LOG2E, sacc[ni][3])); \
    lsum += (p0 + p1) + (p2 + p3);                                             \
    asm("v_cvt_pk_bf16_f32 %0, %1, %2" : "=v"(qp[ni][0]) : "v"(p0), "v"(p1));  \
    asm("v_cvt_pk_bf16_f32 %0, %1, %2" : "=v"(qp[ni][1]) : "v"(p2), "v"(p3));  \
  }                                                                            \
  bf16x8 pf[2];                                                                \
  _Pragma("unroll")                                                            \
  for (int ks = 0; ks < 2; ++ks) {                                             \
    unsigned x0 = qp[2 * ks][0], x1 = qp[2 * ks][1];                           \
    unsigned y0 = qp[2 * ks + 1][0], y1 = qp[2 * ks + 1][1];                   \
    asm("v_permlane32_swap_b32 %0, %1" : "+v"(x0), "+v"(y0));                  \
    asm("v_permlane16_swap_b32 %0, %1" : "+v"(x0), "+v"(y0));                  \
    asm("v_permlane32_swap_b32 %0, %1" : "+v"(x1), "+v"(y1));                  \
    asm("v_permlane16_swap_b32 %0, %1" : "+v"(x1), "+v"(y1));                  \
    u32x4 t_; t_[0] = x0; t_[1] = x1; t_[2] = y0; t_[3] = y1;                  \
    pf[ks] = __builtin_bit_cast(bf16x8, t_);                                   \
  }                                                                            \
  __builtin_amdgcn_s_setprio(1);                                               \
  _Pragma("unroll")                                                            \
  for (int ni = 0; ni < 4; ++ni) {                                             \
    const bf16x8 v0 = *(const bf16x8*)(&Vb[b][0] + 0 * 4096 + ni * 1024 + c * 64 + gsw16); \
    const bf16x8 v1 = *(const bf16x8*)(&Vb[b][0] + 1 * 4096 + ni * 1024 + c * 64 + gsw16); \
    oacc[ni] = __builtin_amdgcn_mfma_f32_16x16x32_bf16(pf[0], v0, oacc[ni], 0, 0, 0); \
    oacc[ni] = __builtin_amdgcn_mfma_f32_16x16x32_bf16(pf[1], v1, oacc[ni], 0, 0, 0); \
  }                                                                            \
  __builtin_amdgcn_s_setprio(0);                                               \
}

__global__ __launch_bounds__(512, 4)
void attn_kernel(const __bf16* __restrict__ qb, const __bf16* __restrict__ ktp,
                 const __bf16* __restrict__ vtp, const float* __restrict__ ab,
                 __bf16* __restrict__ oupb) {
  __shared__ __attribute__((aligned(16))) char Kb[2][8192];
  __shared__ __attribute__((aligned(16))) char Vb[2][8192];
  const int tid = threadIdx.x, w = tid >> 6, lane = tid & 63;
  const int c = lane & 15, g = lane >> 4;
  const int sl16 = (lane ^ ((lane >> 3) & 3)) * 16;   // store-side source swizzle
  const int gsw16 = (g ^ ((c >> 1) & 3)) * 16;        // read-side swizzle
  const int idx = blockIdx.x;                 // rb*32 + bh (bh fastest: same-head blocks share XCD)
  const int bh = idx & 31, rb = idx >> 5;
  const __bf16* qh = qb + (size_t)bh * (2048 * 64);
  const char* kp = (const char*)ktp + (size_t)bh * (32 * 8192);
  const char* vp = (const char*)vtp + (size_t)bh * (32 * 8192);
  const int q0 = rb * 128 + w * 16;
  const float* bprow = ab + (size_t)(q0 + c) * 2048;
  const int b2 = bh >> 4, h = bh & 15;

  bf16x8 qf[2];
#pragma unroll
  for (int ks = 0; ks < 2; ++ks)
    qf[ks] = *(const bf16x8*)(qh + (size_t)(q0 + c) * 64 + ks * 32 + g * 8);

  f32x4 oacc[4];
  float lsum = 0.0f;
#pragma unroll
  for (int ni = 0; ni < 4; ++ni) oacc[ni] = (f32x4)(0.0f);

  STAGE(0, 0);
  __syncthreads();
#pragma unroll 1
  for (int tt = 0; tt < 32; tt += 2) {
    if (tt + 1 < 32) STAGE(tt + 1, 1);
    COMPUTE(tt, 0);
    __syncthreads();
    if (tt + 2 < 32) STAGE(tt + 2, 0);
    COMPUTE(tt + 1, 1);
    __syncthreads();
  }

  // normalize + write bf16 [B, L, H*HD]
  float l = lsum;
  l += __shfl_xor(l, 16, 64);
  l += __shfl_xor(l, 32, 64);   // l = full row sum for q-row c
#pragma unroll
  for (int j = 0; j < 4; ++j) {
    const float lr = __shfl(l, g * 4 + j, 64);
    const float inv = 1.0f / lr;
    const int qrow = q0 + g * 4 + j;
    __bf16* orow = oupb + ((size_t)(b2 * 2048 + qrow) * 16 + h) * 64;
#pragma unroll
    for (int ni = 0; ni < 4; ++ni)
      orow[ni * 16 + c] = (__bf16)(oacc[ni][j] * inv);
  }
}

// ---------------------------------------------------------------- proj GEMM (64x128 tiles, BK=64)
__global__ __launch_bounds__(256, 2)
void gemm_proj_kernel(const __bf16* __restrict__ A, const __bf16* __restrict__ B,
                      const float* __restrict__ b_proj, float* __restrict__ out) {
  __shared__ __attribute__((aligned(16))) __bf16 As[2][64 * 32];
  __shared__ __attribute__((aligned(16))) __bf16 Bs[2][128 * 32];
  const int tid = threadIdx.x;
  const int w = tid >> 6, lane = tid & 63;
  const int c = lane & 15, g = lane >> 4;
  const int m0 = blockIdx.y * 64, n0 = blockIdx.x * 128;
  const int wm = (w >> 1) * 32, wn = (w & 1) * 64;
  f32x4 acc[2][4];
#pragma unroll
  for (int i = 0; i < 2; ++i)
#pragma unroll
    for (int j = 0; j < 4; ++j) acc[i][j] = (f32x4)(0.0f);

  const int r_row = lane >> 2;
  const int r_col = (lane & 3) * 16;
  const char* Abase = (const char*)A + (size_t)m0 * 2048;
  const char* Bbase = (const char*)B + (size_t)n0 * 2048;

  for (int kt = 0; kt < 1024; kt += 64) {
#pragma unroll
    for (int ks = 0; ks < 2; ++ks) {
      {
        const int row = w * 16 + r_row;
        gld16((char*)&As[ks][0] + w * 1024, Abase + (size_t)row * 2048 + kt * 2 + ks * 64 + r_col);
      }
#pragma unroll
      for (int s = 0; s < 2; ++s) {
        const int R = w * 2 + s;
        const int row = R * 16 + r_row;
        gld16((char*)&Bs[ks][0] + R * 1024, Bbase + (size_t)row * 2048 + kt * 2 + ks * 64 + r_col);
      }
    }
    __syncthreads();
#pragma unroll
    for (int ks = 0; ks < 2; ++ks) {
      bf16x8 af[2], bfr[4];
#pragma unroll
      for (int i = 0; i < 2; ++i)
        af[i] = *(const bf16x8*)((const char*)&As[ks][0] + (wm + i * 16 + c) * 64 + g * 16);
#pragma unroll
      for (int i = 0; i < 4; ++i)
        bfr[i] = *(const bf16x8*)((const char*)&Bs[ks][0] + (wn + i * 16 + c) * 64 + g * 16);
#pragma unroll
      for (int mi = 0; mi < 2; ++mi)
#pragma unroll
        for (int ni = 0; ni < 4; ++ni)
          acc[mi][ni] = __builtin_amdgcn_mfma_f32_16x16x32_bf16(af[mi], bfr[ni], acc[mi][ni], 0, 0, 0);
    }
    __syncthreads();
  }

  float cbias[4];
#pragma unroll
  for (int ni = 0; ni < 4; ++ni) cbias[ni] = b_proj[n0 + wn + ni * 16 + c];
#pragma unroll
  for (int mi = 0; mi < 2; ++mi)
#pragma unroll
    for (int j = 0; j < 4; ++j) {
      const int m = m0 + wm + mi * 16 + g * 4 + j;
      float* orow = out + (size_t)m * 1024 + n0 + wn;
#pragma unroll
      for (int ni = 0; ni < 4; ++ni)
        orow[ni * 16 + c] = acc[mi][ni][j] + cbias[ni];
    }
}

// ---------------------------------------------------------------- launch
extern "C" void kernel_launch(void* const* d_in, const int* in_sizes, int n_in,
                              void* d_out, int out_size, void* d_ws, size_t ws_size,
                              hipStream_t stream) {
  const float* x         = (const float*)d_in[0];
  const float* attn_bias = (const float*)d_in[1];
  const float* w_qkv     = (const float*)d_in[2];
  const float* q_bias    = (const float*)d_in[3];
  const float* v_bias    = (const float*)d_in[4];
  const float* scale_mul = (const float*)d_in[5];
  const float* w_proj    = (const float*)d_in[6];
  const float* b_proj    = (const float*)d_in[7];
  float* out = (float*)d_out;

  __bf16* xb     = (__bf16*)d_ws;                 // 8MB (aliased as oupb after gemm_qkv)
  __bf16* wqkvb  = xb + 4194304;                  // 6MB
  __bf16* wprojb = wqkvb + 3145728;               // 2MB
  __bf16* qb     = wprojb + 1048576;              // 8MB (q pre-scaled by log2e)
  __bf16* ktp    = qb + 4194304;                  // 8MB (K fragment-tile order)
  __bf16* vtp    = ktp + 4194304;                 // 8MB (V slot order, written by gemm_qkv)
  __bf16* oupb   = xb;                            // alias: xb dead after gemm_qkv

  prep_kernel<<<2048, 256, 0, stream>>>(x, w_qkv, w_proj, xb, wqkvb, wprojb);
  gemm_qkv_kernel<<<768, 256, 0, stream>>>(xb, wqkvb, q_bias, v_bias, scale_mul,
                                           qb, ktp, vtp);
  attn_kernel<<<512, 512, 0, stream>>>(qb, ktp, vtp, attn_bias, oupb);
  gemm_proj_kernel<<<dim3(8, 64), 256, 0, stream>>>(oupb, wprojb, b_proj, out);
}

// Round 11
// 197.011 us; speedup vs baseline: 1.0895x; 1.0895x over previous
//
#include <hip/hip_runtime.h>
#include <cstdint>
#include <cstddef>
#include <math.h>

typedef __attribute__((ext_vector_type(8))) __bf16 bf16x8;
typedef __attribute__((ext_vector_type(4))) __bf16 bf16x4;
typedef __attribute__((ext_vector_type(4))) float f32x4;
typedef __attribute__((ext_vector_type(4))) unsigned int u32x4;

#define AS1 __attribute__((address_space(1)))
#define AS3 __attribute__((address_space(3)))

#define LOG2E 1.4426950408889634f

__device__ __forceinline__ void gld16(void* lds_uniform, const void* gaddr) {
  __builtin_amdgcn_global_load_lds((const AS1 unsigned int*)gaddr,
                                   (AS3 unsigned int*)lds_uniform, 16, 0, 0);
}

// ---------------------------------------------------------------- prep: fp32->bf16 casts + bias rearrange
// cast part: 2048 blocks x 4 float4/thread. bias part: 512 blocks.
// btr layout: [qt16 0..127][ktile 0..31][lane 0..63][16 values]
//   lane (c,g) values v'=ni*4+j = bias[qt16*16 + c][ktile*64 + ni*16 + g*4 + j] * LOG2E
__global__ __launch_bounds__(256)
void prep_kernel(const float* __restrict__ x, const float* __restrict__ wqkv,
                 const float* __restrict__ wproj, const float* __restrict__ bias,
                 __bf16* __restrict__ xb, __bf16* __restrict__ wqkvb,
                 __bf16* __restrict__ wprojb, __bf16* __restrict__ btr) {
  __shared__ __bf16 T[32][264];
  const int b = blockIdx.x;
  const int tid = threadIdx.x;
  if (b < 2048) {
    const float* src; __bf16* dst; int fb;
    if (b < 1024)      { src = x;     dst = xb;     fb = b; }
    else if (b < 1792) { src = wqkv;  dst = wqkvb;  fb = b - 1024; }
    else               { src = wproj; dst = wprojb; fb = b - 1792; }
#pragma unroll
    for (int q = 0; q < 4; ++q) {
      const size_t i = ((size_t)fb * 1024 + q * 256 + tid) * 4;
      const float4 v = *(const float4*)(src + i);
      bf16x4 o;
      o[0] = (__bf16)v.x; o[1] = (__bf16)v.y; o[2] = (__bf16)v.z; o[3] = (__bf16)v.w;
      *(bf16x4*)(dst + i) = o;
    }
    return;
  }
  const int bb = b - 2048;
  const int rb = bb >> 3, cg = bb & 7;
  const float* src = bias + (size_t)(rb * 32) * 2048 + cg * 256;
#pragma unroll
  for (int i = 0; i < 8; ++i) {
    const int u = i * 256 + tid;
    const int r = u >> 6, c4 = (u & 63) * 4;
    const float4 v = *(const float4*)(src + (size_t)r * 2048 + c4);
    T[r][c4 + 0] = (__bf16)(v.x * LOG2E);
    T[r][c4 + 1] = (__bf16)(v.y * LOG2E);
    T[r][c4 + 2] = (__bf16)(v.z * LOG2E);
    T[r][c4 + 3] = (__bf16)(v.w * LOG2E);
  }
  __syncthreads();
  const int ktl = tid >> 6;
  const int lane = tid & 63, g = lane >> 4, cc = lane & 15;
#pragma unroll
  for (int sub = 0; sub < 2; ++sub) {
    __bf16 outv[16];
#pragma unroll
    for (int v = 0; v < 16; ++v) {
      const int ni = v >> 2, j = v & 3;
      outv[v] = T[sub * 16 + cc][ktl * 64 + ni * 16 + g * 4 + j];
    }
    __bf16* dst = btr + ((size_t)(((rb * 2 + sub) * 32) + cg * 4 + ktl) * 64 + lane) * 16;
    *(bf16x8*)(dst) = *(bf16x8*)(outv);
    *(bf16x8*)(dst + 8) = *(bf16x8*)(outv + 8);
  }
}

// ---------------------------------------------------------------- QKV GEMM v5 (verified): 4-wave, 64x64/wave,
// BK=64, grid 768, bijective XCD swizzle, launch_bounds(256,3) -> 3 blocks/CU, V epilogue
// staged through wave-private LDS for coalesced bf16x8 stores.
__global__ __launch_bounds__(256, 3)
void gemm_qkv_kernel(const __bf16* __restrict__ A, const __bf16* __restrict__ B,
                     const float* __restrict__ q_bias, const float* __restrict__ v_bias,
                     const float* __restrict__ scale_mul,
                     __bf16* __restrict__ qb, __bf16* __restrict__ ktp, __bf16* __restrict__ vtp) {
  __shared__ __attribute__((aligned(16))) __bf16 As[2][128 * 32];
  __shared__ __attribute__((aligned(16))) __bf16 Bs[2][128 * 32];
  const int tid = threadIdx.x;
  const int w = tid >> 6, lane = tid & 63;
  const int bid = blockIdx.x;
  const int swz = (bid & 7) * 96 + (bid >> 3);    // 768 % 8 == 0 -> bijective
  const int m0 = (swz / 24) * 128, n0 = (swz % 24) * 128;
  const int wm = (w >> 1) * 64, wn = (w & 1) * 64;
  const int c = lane & 15, g = lane >> 4;
  f32x4 acc[4][4];  // [ni][mi]
#pragma unroll
  for (int i = 0; i < 4; ++i)
#pragma unroll
    for (int j = 0; j < 4; ++j) acc[i][j] = (f32x4)(0.0f);

  const int r_row = lane >> 2;
  const int r_col = (lane & 3) * 16;
  const char* Abase = (const char*)A + (size_t)m0 * 2048;
  const char* Bbase = (const char*)B + (size_t)n0 * 2048;

  for (int kt = 0; kt < 1024; kt += 64) {
#pragma unroll
    for (int ks = 0; ks < 2; ++ks)
#pragma unroll
      for (int s = 0; s < 2; ++s) {
        const int R = w * 2 + s;
        const int row = R * 16 + r_row;
        gld16((char*)&As[ks][0] + R * 1024, Abase + (size_t)row * 2048 + kt * 2 + ks * 64 + r_col);
        gld16((char*)&Bs[ks][0] + R * 1024, Bbase + (size_t)row * 2048 + kt * 2 + ks * 64 + r_col);
      }
    __syncthreads();
#pragma unroll
    for (int ks = 0; ks < 2; ++ks) {
      bf16x8 af[4], bfr[4];
#pragma unroll
      for (int i = 0; i < 4; ++i) {
        af[i]  = *(const bf16x8*)((const char*)&As[ks][0] + (wm + i * 16 + c) * 64 + g * 16);
        bfr[i] = *(const bf16x8*)((const char*)&Bs[ks][0] + (wn + i * 16 + c) * 64 + g * 16);
      }
#pragma unroll
      for (int ni = 0; ni < 4; ++ni)
#pragma unroll
        for (int mi = 0; mi < 4; ++mi)
          acc[ni][mi] = __builtin_amdgcn_mfma_f32_16x16x32_bf16(bfr[ni], af[mi], acc[ni][mi], 0, 0, 0);
    }
    __syncthreads();
  }

  const int nbase = n0 + wn;
  const int which = nbase >> 10;
  const int h = (nbase >> 6) & 15;
  float smh = 1.0f;
  if (which == 0) smh = __expf(fminf(scale_mul[h], 4.605170185988091f)) * LOG2E;
  float4 cb[4];
#pragma unroll
  for (int ni = 0; ni < 4; ++ni) {
    if (which == 0)      cb[ni] = *(const float4*)(q_bias + nbase + ni * 16 + 4 * g);
    else if (which == 2) cb[ni] = *(const float4*)(v_bias + nbase - 2048 + ni * 16 + 4 * g);
    else                 cb[ni] = make_float4(0.f, 0.f, 0.f, 0.f);
  }
  const int mrow0 = m0 + wm;
  const int b2 = mrow0 >> 11;
  const int lpos0 = mrow0 & 2047;
  __bf16* kt_tile = ktp + (size_t)(b2 * 16 + h) * 131072 + (size_t)(lpos0 >> 6) * 4096;
  __bf16* dst_q = qb + ((size_t)((b2 * 16 + h) * 2048 + lpos0)) * 64;
  __bf16* vtile = vtp + ((size_t)((b2 * 16 + h) * 32) + (lpos0 >> 6)) * 4096;
  __bf16* Ls = (__bf16*)((char*)&As[0][0] + w * 8192);  // wave-private, dead after K-loop

#pragma unroll
  for (int mi = 0; mi < 4; ++mi) {
    float v[4][4];
#pragma unroll
    for (int ni = 0; ni < 4; ++ni) {
      v[ni][0] = acc[ni][mi][0] + cb[ni].x;
      v[ni][1] = acc[ni][mi][1] + cb[ni].y;
      v[ni][2] = acc[ni][mi][2] + cb[ni].z;
      v[ni][3] = acc[ni][mi][3] + cb[ni].w;
    }
    const int key = mi * 16 + c;
    if (which == 2) {
      // V: stage to wave-private LDS in slot order (sc == 1, no normalize)
      const int ks2 = mi >> 1;
      const int gg  = ((mi & 1) << 1) | (c >> 3);
      const int e   = c & 7;
      __bf16* basep = Ls + ks2 * 2048 + gg * 8 + e;
#pragma unroll
      for (int ni = 0; ni < 4; ++ni)
#pragma unroll
        for (int j = 0; j < 4; ++j)
          basep[ni * 512 + (4 * g + j) * 32] = (__bf16)v[ni][j];
    } else {
      float ss = 0.0f;
#pragma unroll
      for (int ni = 0; ni < 4; ++ni)
#pragma unroll
        for (int j = 0; j < 4; ++j) ss += v[ni][j] * v[ni][j];
      ss += __shfl_xor(ss, 16, 64);
      ss += __shfl_xor(ss, 32, 64);
      const float sc = rsqrtf(ss) * smh;
      if (which == 1) {
#pragma unroll
        for (int ni = 0; ni < 4; ++ni) {
          bf16x4 pk;
          pk[0] = (__bf16)(v[ni][0] * sc); pk[1] = (__bf16)(v[ni][1] * sc);
          pk[2] = (__bf16)(v[ni][2] * sc); pk[3] = (__bf16)(v[ni][3] * sc);
          *(bf16x4*)(kt_tile + (ni >> 1) * 2048 + key * 32 + (ni & 1) * 16 + 4 * g) = pk;
        }
      } else {
        __bf16* drow = dst_q + (size_t)key * 64;
#pragma unroll
        for (int ni = 0; ni < 4; ++ni) {
          bf16x4 pk;
          pk[0] = (__bf16)(v[ni][0] * sc); pk[1] = (__bf16)(v[ni][1] * sc);
          pk[2] = (__bf16)(v[ni][2] * sc); pk[3] = (__bf16)(v[ni][3] * sc);
          *(bf16x4*)(drow + ni * 16 + 4 * g) = pk;
        }
      }
    }
  }
  if (which == 2) {
    // coalesced readback + store: 8 x 1KB bf16x8 per wave
#pragma unroll
    for (int r = 0; r < 8; ++r) {
      const int o = r * 512 + lane * 8;
      *(bf16x8*)(vtile + o) = *(const bf16x8*)(Ls + o);
    }
  }
}

// ---------------------------------------------------------------- flash attention v17
// = v13 (verified best) + bias refill moved to AFTER its last use: bA0/bA1 for tile t+1
// are loaded right after softmax(t) consumes them -> next use is PV + barrier + QK away,
// and the barrier's vmcnt(0) drain (already paid for STAGE) retires them for free.
// Zero extra registers (same two regs, refilled earlier).
#define STAGE(t, b) {                                                          \
  const char* _ks = kp + (size_t)(t) * 8192 + w * 1024 + sl16;                 \
  const char* _vs = vp + (size_t)(t) * 8192 + w * 1024 + sl16;                 \
  gld16(&Kb[b][w * 1024], _ks);                                                \
  gld16(&Vb[b][w * 1024], _vs);                                                \
}

#define BAV(ni, j) ((ni * 4 + j < 8) ? bA0[(ni * 4 + j) & 7] : bA1[(ni * 4 + j) & 7])

#define COMPUTE(t, b) {                                                        \
  bf16x8 kf[4][2];                                                             \
  _Pragma("unroll")                                                            \
  for (int ni = 0; ni < 4; ++ni)                                               \
    _Pragma("unroll")                                                          \
    for (int ks = 0; ks < 2; ++ks)                                             \
      kf[ni][ks] = *(const bf16x8*)(&Kb[b][0] + ks * 4096 + (ni * 16 + c) * 64 + gsw16); \
  f32x4 sacc[4];                                                               \
  __builtin_amdgcn_s_setprio(1);                                               \
  _Pragma("unroll")                                                            \
  for (int ni = 0; ni < 4; ++ni) {                                             \
    f32x4 s_ = __builtin_amdgcn_mfma_f32_16x16x32_bf16(kf[ni][0], qf[0], (f32x4)(0.0f), 0, 0, 0); \
    sacc[ni] = __builtin_amdgcn_mfma_f32_16x16x32_bf16(kf[ni][1], qf[1], s_, 0, 0, 0); \
  }                                                                            \
  __builtin_amdgcn_s_setprio(0);                                               \
  unsigned qp[4][2];                                                           \
  _Pragma("unroll")                                                            \
  for (int ni = 0; ni < 4; ++ni) {                                             \
    const float p0 = __builtin_amdgcn_exp2f(sacc[ni][0] + (float)BAV(ni, 0));  \
    const float p1 = __builtin_amdgcn_exp2f(sacc[ni][1] + (float)BAV(ni, 1));  \
    const float p2 = __builtin_amdgcn_exp2f(sacc[ni][2] + (float)BAV(ni, 2));  \
    const float p3 = __builtin_amdgcn_exp2f(sacc[ni][3] + (float)BAV(ni, 3));  \
    lsum += (p0 + p1) + (p2 + p3);                                             \
    asm("v_cvt_pk_bf16_f32 %0, %1, %2" : "=v"(qp[ni][0]) : "v"(p0), "v"(p1));  \
    asm("v_cvt_pk_bf16_f32 %0, %1, %2" : "=v"(qp[ni][1]) : "v"(p2), "v"(p3));  \
  }                                                                            \
  { /* refill bias for next tile (issued after last use; hidden under PV+barrier+QK) */ \
    const int _tn = ((t) < 31) ? ((t) + 1) : 31;                               \
    const char* _bb = bp + (size_t)_tn * 2048 + lane * 32;                     \
    bA0 = *(const bf16x8*)_bb;                                                 \
    bA1 = *(const bf16x8*)(_bb + 16);                                          \
  }                                                                            \
  bf16x8 pf[2];                                                                \
  _Pragma("unroll")                                                            \
  for (int ks = 0; ks < 2; ++ks) {                                             \
    unsigned x0 = qp[2 * ks][0], x1 = qp[2 * ks][1];                           \
    unsigned y0 = qp[2 * ks + 1][0], y1 = qp[2 * ks + 1][1];                   \
    asm("v_permlane32_swap_b32 %0, %1" : "+v"(x0), "+v"(y0));                  \
    asm("v_permlane16_swap_b32 %0, %1" : "+v"(x0), "+v"(y0));                  \
    asm("v_permlane32_swap_b32 %0, %1" : "+v"(x1), "+v"(y1));                  \
    asm("v_permlane16_swap_b32 %0, %1" : "+v"(x1), "+v"(y1));                  \
    u32x4 t_; t_[0] = x0; t_[1] = x1; t_[2] = y0; t_[3] = y1;                  \
    pf[ks] = __builtin_bit_cast(bf16x8, t_);                                   \
  }                                                                            \
  __builtin_amdgcn_s_setprio(1);                                               \
  _Pragma("unroll")                                                            \
  for (int ni = 0; ni < 4; ++ni) {                                             \
    const bf16x8 v0 = *(const bf16x8*)(&Vb[b][0] + 0 * 4096 + ni * 1024 + c * 64 + gsw16); \
    const bf16x8 v1 = *(const bf16x8*)(&Vb[b][0] + 1 * 4096 + ni * 1024 + c * 64 + gsw16); \
    oacc[ni] = __builtin_amdgcn_mfma_f32_16x16x32_bf16(pf[0], v0, oacc[ni], 0, 0, 0); \
    oacc[ni] = __builtin_amdgcn_mfma_f32_16x16x32_bf16(pf[1], v1, oacc[ni], 0, 0, 0); \
  }                                                                            \
  __builtin_amdgcn_s_setprio(0);                                               \
}

__global__ __launch_bounds__(512, 4)
void attn_kernel(const __bf16* __restrict__ qb, const __bf16* __restrict__ ktp,
                 const __bf16* __restrict__ vtp, const __bf16* __restrict__ btr,
                 __bf16* __restrict__ oupb) {
  __shared__ __attribute__((aligned(16))) char Kb[2][8192];
  __shared__ __attribute__((aligned(16))) char Vb[2][8192];
  const int tid = threadIdx.x, w = tid >> 6, lane = tid & 63;
  const int c = lane & 15, g = lane >> 4;
  const int sl16 = (lane ^ ((lane >> 3) & 3)) * 16;   // store-side source swizzle
  const int gsw16 = (g ^ ((c >> 1) & 3)) * 16;        // read-side swizzle
  const int idx = blockIdx.x;                 // rb*32 + bh (bh fastest: same-head blocks share XCD)
  const int bh = idx & 31, rb = idx >> 5;
  const __bf16* qh = qb + (size_t)bh * (2048 * 64);
  const char* kp = (const char*)ktp + (size_t)bh * (32 * 8192);
  const char* vp = (const char*)vtp + (size_t)bh * (32 * 8192);
  const char* bp = (const char*)btr + (size_t)(rb * 8 + w) * 65536;
  const int q0 = rb * 128 + w * 16;
  const int b2 = bh >> 4, h = bh & 15;

  bf16x8 qf[2];
#pragma unroll
  for (int ks = 0; ks < 2; ++ks)
    qf[ks] = *(const bf16x8*)(qh + (size_t)(q0 + c) * 64 + ks * 32 + g * 8);

  // prologue bias load for tile 0
  bf16x8 bA0 = *(const bf16x8*)(bp + lane * 32);
  bf16x8 bA1 = *(const bf16x8*)(bp + lane * 32 + 16);

  f32x4 oacc[4];
  float lsum = 0.0f;
#pragma unroll
  for (int ni = 0; ni < 4; ++ni) oacc[ni] = (f32x4)(0.0f);

  STAGE(0, 0);
  __syncthreads();
#pragma unroll 1
  for (int tt = 0; tt < 32; tt += 2) {
    if (tt + 1 < 32) STAGE(tt + 1, 1);
    COMPUTE(tt, 0);
    __syncthreads();
    if (tt + 2 < 32) STAGE(tt + 2, 0);
    COMPUTE(tt + 1, 1);
    __syncthreads();
  }

  // normalize + write bf16 [B, L, H*HD]
  float l = lsum;
  l += __shfl_xor(l, 16, 64);
  l += __shfl_xor(l, 32, 64);   // l = full row sum for q-row c
#pragma unroll
  for (int j = 0; j < 4; ++j) {
    const float lr = __shfl(l, g * 4 + j, 64);
    const float inv = 1.0f / lr;
    const int qrow = q0 + g * 4 + j;
    __bf16* orow = oupb + ((size_t)(b2 * 2048 + qrow) * 16 + h) * 64;
#pragma unroll
    for (int ni = 0; ni < 4; ++ni)
      orow[ni * 16 + c] = (__bf16)(oacc[ni][j] * inv);
  }
}

// ---------------------------------------------------------------- proj GEMM (64x128 tiles, BK=64)
__global__ __launch_bounds__(256, 2)
void gemm_proj_kernel(const __bf16* __restrict__ A, const __bf16* __restrict__ B,
                      const float* __restrict__ b_proj, float* __restrict__ out) {
  __shared__ __attribute__((aligned(16))) __bf16 As[2][64 * 32];
  __shared__ __attribute__((aligned(16))) __bf16 Bs[2][128 * 32];
  const int tid = threadIdx.x;
  const int w = tid >> 6, lane = tid & 63;
  const int c = lane & 15, g = lane >> 4;
  const int m0 = blockIdx.y * 64, n0 = blockIdx.x * 128;
  const int wm = (w >> 1) * 32, wn = (w & 1) * 64;
  f32x4 acc[2][4];
#pragma unroll
  for (int i = 0; i < 2; ++i)
#pragma unroll
    for (int j = 0; j < 4; ++j) acc[i][j] = (f32x4)(0.0f);

  const int r_row = lane >> 2;
  const int r_col = (lane & 3) * 16;
  const char* Abase = (const char*)A + (size_t)m0 * 2048;
  const char* Bbase = (const char*)B + (size_t)n0 * 2048;

  for (int kt = 0; kt < 1024; kt += 64) {
#pragma unroll
    for (int ks = 0; ks < 2; ++ks) {
      {
        const int row = w * 16 + r_row;
        gld16((char*)&As[ks][0] + w * 1024, Abase + (size_t)row * 2048 + kt * 2 + ks * 64 + r_col);
      }
#pragma unroll
      for (int s = 0; s < 2; ++s) {
        const int R = w * 2 + s;
        const int row = R * 16 + r_row;
        gld16((char*)&Bs[ks][0] + R * 1024, Bbase + (size_t)row * 2048 + kt * 2 + ks * 64 + r_col);
      }
    }
    __syncthreads();
#pragma unroll
    for (int ks = 0; ks < 2; ++ks) {
      bf16x8 af[2], bfr[4];
#pragma unroll
      for (int i = 0; i < 2; ++i)
        af[i] = *(const bf16x8*)((const char*)&As[ks][0] + (wm + i * 16 + c) * 64 + g * 16);
#pragma unroll
      for (int i = 0; i < 4; ++i)
        bfr[i] = *(const bf16x8*)((const char*)&Bs[ks][0] + (wn + i * 16 + c) * 64 + g * 16);
#pragma unroll
      for (int mi = 0; mi < 2; ++mi)
#pragma unroll
        for (int ni = 0; ni < 4; ++ni)
          acc[mi][ni] = __builtin_amdgcn_mfma_f32_16x16x32_bf16(af[mi], bfr[ni], acc[mi][ni], 0, 0, 0);
    }
    __syncthreads();
  }

  float cbias[4];
#pragma unroll
  for (int ni = 0; ni < 4; ++ni) cbias[ni] = b_proj[n0 + wn + ni * 16 + c];
#pragma unroll
  for (int mi = 0; mi < 2; ++mi)
#pragma unroll
    for (int j = 0; j < 4; ++j) {
      const int m = m0 + wm + mi * 16 + g * 4 + j;
      float* orow = out + (size_t)m * 1024 + n0 + wn;
#pragma unroll
      for (int ni = 0; ni < 4; ++ni)
        orow[ni * 16 + c] = acc[mi][ni][j] + cbias[ni];
    }
}

// ---------------------------------------------------------------- launch
extern "C" void kernel_launch(void* const* d_in, const int* in_sizes, int n_in,
                              void* d_out, int out_size, void* d_ws, size_t ws_size,
                              hipStream_t stream) {
  const float* x         = (const float*)d_in[0];
  const float* attn_bias = (const float*)d_in[1];
  const float* w_qkv     = (const float*)d_in[2];
  const float* q_bias    = (const float*)d_in[3];
  const float* v_bias    = (const float*)d_in[4];
  const float* scale_mul = (const float*)d_in[5];
  const float* w_proj    = (const float*)d_in[6];
  const float* b_proj    = (const float*)d_in[7];
  float* out = (float*)d_out;

  __bf16* xb     = (__bf16*)d_ws;                 // 8MB (aliased as oupb after gemm_qkv)
  __bf16* wqkvb  = xb + 4194304;                  // 6MB
  __bf16* wprojb = wqkvb + 3145728;               // 2MB
  __bf16* qb     = wprojb + 1048576;              // 8MB (q pre-scaled by log2e)
  __bf16* ktp    = qb + 4194304;                  // 8MB (K fragment-tile order)
  __bf16* vtp    = ktp + 4194304;                 // 8MB (V slot order, written by gemm_qkv)
  __bf16* btr    = vtp + 4194304;                 // 8MB (bias, *log2e)
  __bf16* oupb   = xb;                            // alias: xb dead after gemm_qkv

  prep_kernel<<<2560, 256, 0, stream>>>(x, w_qkv, w_proj, attn_bias, xb, wqkvb, wprojb, btr);
  gemm_qkv_kernel<<<768, 256, 0, stream>>>(xb, wqkvb, q_bias, v_bias, scale_mul,
                                           qb, ktp, vtp);
  attn_kernel<<<512, 512, 0, stream>>>(qb, ktp, vtp, btr, oupb);
  gemm_proj_kernel<<<dim3(8, 64), 256, 0, stream>>>(oupb, wprojb, b_proj, out);
}